// Round 5
// baseline (236.108 us; speedup 1.0000x reference)
//
#include <hip/hip_runtime.h>
#include <stdint.h>

#define SEQ 41
#define KG 8
#define MM 5
#define SITE 20

typedef float f32x4 __attribute__((ext_vector_type(4)));
typedef short bf16x8 __attribute__((ext_vector_type(8)));
typedef unsigned int u32x4 __attribute__((ext_vector_type(4)));

union FragU { u32x4 u; bf16x8 h; };

__device__ __forceinline__ unsigned short f2bf(float f) {
    union { float f; uint32_t u; } v; v.f = f;
    uint32_t u = v.u;
    u += 0x7fffu + ((u >> 16) & 1u);   // round-to-nearest-even
    return (unsigned short)(u >> 16);
}

// truncating pack of two f32 -> one dword of 2 bf16 (consistent with r4, passed)
__device__ __forceinline__ uint32_t pk2(float a, float b) {
    union { float f; uint32_t u; } ua, ub; ua.f = a; ub.f = b;
    return (ua.u >> 16) | (ub.u & 0xffff0000u);
}

// unaligned-safe 16B load (batch base is only 4B-aligned)
__device__ __forceinline__ f32x4 ld4u(const float* p) {
    f32x4 v; __builtin_memcpy(&v, p, 16); return v;
}

// exact-shape fast tanh: 1 - 2/(e^{2x}+1); correct limits at +/-inf
__device__ __forceinline__ float fast_tanh(float x) {
    float e = __builtin_amdgcn_exp2f(x * 2.8853900817779268f);  // e^{2x}
    return 1.0f - 2.0f * __builtin_amdgcn_rcpf(e + 1.0f);
}

// ---------------- Kernel 0: weight fragment precompute (runs once/call) ----
// Layout: wf_u16[f*512 + lane*8 + j], f=(k*2+ks)*3+mt; A[m=o][K=i]=w1d[(o*41+i)*3+k]
__global__ void k_wprep(const float* __restrict__ w1d, unsigned short* __restrict__ wf) {
    for (int p = threadIdx.x; p < 18 * 64; p += 256) {
        int f = p >> 6, lane = p & 63;
        int k = f / 6, ks = (f / 3) % 2, mt = f % 3;
        int o = mt * 16 + (lane & 15);
#pragma unroll
        for (int j = 0; j < 8; ++j) {
            int i = ks * 32 + (lane >> 4) * 8 + j;
            float v = (o < SEQ && i < SEQ) ? w1d[(o * SEQ + i) * 3 + k] : 0.0f;
            wf[(size_t)p * 8 + j] = f2bf(v);
        }
    }
}

// ---------------- Kernel 1: subgraph selection (one WAVE per batch) ---------
__device__ __forceinline__ int wave_argmax(float v) {
    float m = v;
#pragma unroll
    for (int off = 32; off; off >>= 1) {
        float o = __shfl_xor(m, off);
        m = fmaxf(m, o);
    }
    unsigned long long bal = __ballot(v == m);
    return __ffsll((unsigned long long)bal) - 1;
}

__global__ __launch_bounds__(256) void k_select(const float* __restrict__ att,
                                                const float* __restrict__ deg,
                                                float* __restrict__ out_idx, int B) {
    const int wid = threadIdx.x >> 6;
    const int lane = threadIdx.x & 63;
    const int b = blockIdx.x * 4 + wid;
    if (b >= B) return;

    float dv = (lane < SEQ) ? deg[(size_t)b * SEQ + lane] : -1e30f;
    const float* abase = att + (size_t)b * SEQ * SEQ;
    float* outp = out_idx + (size_t)b * (KG * MM);

    // top-8 of degree depends only on degree: compute all bi upfront...
    int bis[KG];
#pragma unroll
    for (int g = 0; g < KG; ++g) {
        int bi = wave_argmax(dv);
        if (lane == bi) dv = -1e30f;
        bis[g] = bi;
    }
    // ...then issue all 8 row loads together (8 outstanding, latency overlapped)
    float rv[KG];
#pragma unroll
    for (int g = 0; g < KG; ++g)
        rv[g] = (lane < SEQ) ? abase[(size_t)bis[g] * SEQ + lane] : -1e30f;

    bool my_sel = (lane == SITE);
#pragma unroll
    for (int g = 0; g < KG; ++g) {
        float r = my_sel ? -1e30f : rv[g];
        unsigned long long grp = 0;
#pragma unroll
        for (int m = 0; m < MM; ++m) {
            int pi = wave_argmax(r);
            if (lane == pi) { r = -1e30f; my_sel = true; }
            grp |= 1ull << pi;
        }
        if (lane < MM) {
            unsigned long long gg = grp;
            for (int t = 0; t < lane; ++t) gg &= gg - 1;
            outp[g * MM + lane] = (float)(__ffsll((unsigned long long)gg) - 1);
        }
    }
}

// ---------------- Kernel 2: conv1d + double tanh via bf16 MFMA, NO LDS ------
// out[b,o,h] = tanh(tanh( b1[o] + sum_k sum_i x[b,h+k-1,i] * w1d[o,i,k] ))
// B-frag for lane (kgrp,h16), tap kc, tile nt: 8 consecutive floats of row
// r = nt*16+h16+kc-1, cols ks*32+kgrp*8..+7 -> direct global loads, pack to bf16.
// K-padding (cols>=41) and row-padding (r<0 or r>40) are register zeros.
__global__ __launch_bounds__(256) void k_conv1d(const float* __restrict__ x,
                                                const bf16x8* __restrict__ wf,
                                                const float* __restrict__ b1d,
                                                float* __restrict__ out_site,
                                                float* __restrict__ out_asite, int B) {
    const int tid = threadIdx.x;
    const int wid = tid >> 6;
    const int lane = tid & 63;
    const int b = blockIdx.x * 4 + wid;
    const int h16 = lane & 15;
    const int kgrp = lane >> 4;

    // A fragments: 18 coalesced 16B loads from precomputed d_ws (L2-hot)
    bf16x8 afr[18];
#pragma unroll
    for (int f = 0; f < 18; ++f) afr[f] = wf[f * 64 + lane];

    const float* xb = x + (size_t)b * (SEQ * SEQ);

    // Asite: exact f32 copy of row 20
    if (lane < SEQ) out_asite[(size_t)b * SEQ + lane] = xb[SITE * SEQ + lane];

    // hoist bias (12 distinct o per lane)
    float bias[3][4];
#pragma unroll
    for (int mt = 0; mt < 3; ++mt)
#pragma unroll
        for (int j = 0; j < 4; ++j) {
            int o = mt * 16 + kgrp * 4 + j;
            bias[mt][j] = (o < SEQ) ? b1d[o] : 0.0f;
        }

    f32x4 acc[3][3];
#pragma unroll
    for (int a = 0; a < 3; ++a)
#pragma unroll
        for (int n = 0; n < 3; ++n)
#pragma unroll
            for (int j = 0; j < 4; ++j) acc[a][n][j] = 0.0f;

#pragma unroll
    for (int kc = 0; kc < 3; ++kc) {
        FragU P0[3], P1[3];
#pragma unroll
        for (int nt = 0; nt < 3; ++nt) {
            int r = nt * 16 + h16 + kc - 1;
            bool ok = (r >= 0) && (r < SEQ);
            const float* rp = xb + (ok ? r * SEQ : 0);
            // ks=0: cols kgrp*8 .. +7 (max 31 < 41, always in-bounds)
            f32x4 lo = ld4u(rp + kgrp * 8);
            f32x4 hi = ld4u(rp + kgrp * 8 + 4);
            u32x4 p0;
            p0[0] = pk2(lo[0], lo[1]); p0[1] = pk2(lo[2], lo[3]);
            p0[2] = pk2(hi[0], hi[1]); p0[3] = pk2(hi[2], hi[3]);
            // ks=1: kgrp0 -> cols 32..39; kgrp1 -> col 40 only; kgrp>=2 -> zeros
            u32x4 p1 = {0u, 0u, 0u, 0u};
            if (kgrp == 0) {
                f32x4 l2 = ld4u(rp + 32);
                f32x4 h2 = ld4u(rp + 36);
                p1[0] = pk2(l2[0], l2[1]); p1[1] = pk2(l2[2], l2[3]);
                p1[2] = pk2(h2[0], h2[1]); p1[3] = pk2(h2[2], h2[3]);
            } else if (kgrp == 1) {
                p1[0] = pk2(rp[40], 0.0f);
            }
            if (!ok) {
#pragma unroll
                for (int q = 0; q < 4; ++q) { p0[q] = 0u; p1[q] = 0u; }
            }
            P0[nt].u = p0; P1[nt].u = p1;
        }
#pragma unroll
        for (int nt = 0; nt < 3; ++nt) {
#pragma unroll
            for (int mt = 0; mt < 3; ++mt)
                acc[mt][nt] = __builtin_amdgcn_mfma_f32_16x16x32_bf16(
                    afr[(kc * 2 + 0) * 3 + mt], P0[nt].h, acc[mt][nt], 0, 0, 0);
#pragma unroll
            for (int mt = 0; mt < 3; ++mt)
                acc[mt][nt] = __builtin_amdgcn_mfma_f32_16x16x32_bf16(
                    afr[(kc * 2 + 1) * 3 + mt], P1[nt].h, acc[mt][nt], 0, 0, 0);
        }
    }

    // epilogue: +bias, double fast-tanh, predicated store
    float* outb = out_site + (size_t)b * (SEQ * SEQ);
#pragma unroll
    for (int mt = 0; mt < 3; ++mt) {
#pragma unroll
        for (int nt = 0; nt < 3; ++nt) {
            int h = nt * 16 + h16;
#pragma unroll
            for (int j = 0; j < 4; ++j) {
                int o = mt * 16 + kgrp * 4 + j;
                if (o < SEQ && h < SEQ) {
                    float v = acc[mt][nt][j] + bias[mt][j];
                    outb[o * SEQ + h] = fast_tanh(fast_tanh(v));
                }
            }
        }
    }
}

// ---------------- Kernel 3: gather + conv2d (block per batch) — unchanged ---
__global__ __launch_bounds__(256) void k_conv2d(const float* __restrict__ x,
                                                const float* __restrict__ w2,
                                                const float* __restrict__ b2,
                                                const float* __restrict__ idxf,
                                                float* __restrict__ out_bag, int B) {
    const int b = blockIdx.x;
    const int tid = threadIdx.x;
    __shared__ float ctx[KG][MM + 2][SEQ + 3];  // [8][7][44], zero border
    __shared__ int ridx[KG * MM];

    if (tid < KG * MM) ridx[tid] = (int)idxf[(size_t)b * KG * MM + tid];
    float* cz = &ctx[0][0][0];
    for (int t = tid; t < KG * (MM + 2) * (SEQ + 3); t += 256) cz[t] = 0.0f;
    __syncthreads();

    const float* xbp = x + (size_t)b * SEQ * SEQ;
    for (int t = tid; t < KG * MM * SEQ; t += 256) {
        int i = t / (MM * SEQ);
        int rem = t % (MM * SEQ);
        int m = rem / SEQ;
        int w = rem % SEQ;
        ctx[i][m + 1][w + 1] = xbp[ridx[i * MM + m] * SEQ + w];
    }
    __syncthreads();

    if (tid < MM * SEQ) {
        int m = tid / SEQ, w = tid % SEQ;
        float acc[KG];
#pragma unroll
        for (int o = 0; o < KG; ++o) acc[o] = b2[o];
#pragma unroll
        for (int i = 0; i < KG; ++i)
#pragma unroll
            for (int kh = 0; kh < 3; ++kh)
#pragma unroll
                for (int kw = 0; kw < 3; ++kw) {
                    float cv = ctx[i][m + kh][w + kw];
#pragma unroll
                    for (int o = 0; o < KG; ++o)
                        acc[o] += cv * w2[((o * KG + i) * 3 + kh) * 3 + kw];
                }
        size_t base = (size_t)b * KG * MM * SEQ + (size_t)m * SEQ + w;
#pragma unroll
        for (int o = 0; o < KG; ++o)
            out_bag[base + (size_t)o * MM * SEQ] = acc[o];
    }
}

extern "C" void kernel_launch(void* const* d_in, const int* in_sizes, int n_in,
                              void* d_out, int out_size, void* d_ws, size_t ws_size,
                              hipStream_t stream) {
    const float* att = (const float*)d_in[0];
    const float* deg = (const float*)d_in[1];
    const float* x   = (const float*)d_in[2];
    const float* w1d = (const float*)d_in[3];
    const float* b1d = (const float*)d_in[4];
    const float* w2d = (const float*)d_in[5];
    const float* b2d = (const float*)d_in[6];
    const int B = in_sizes[1] / SEQ;  // degree is [B, SEQ]

    float* out = (float*)d_out;
    const size_t s_bag   = (size_t)B * KG * MM * SEQ;  // x_bag  [B,8,5,41]
    const size_t s_asite = (size_t)B * SEQ;            // Asite  [B,1,41]
    const size_t s_site  = (size_t)B * SEQ * SEQ;      // x_site [B,41,41]
    float* o_bag   = out;
    float* o_asite = out + s_bag;
    float* o_site  = out + s_bag + s_asite;
    float* o_idx   = out + s_bag + s_asite + s_site;   // index_all as f32 [B,8,5]

    k_wprep<<<1, 256, 0, stream>>>(w1d, (unsigned short*)d_ws);
    k_select<<<(B + 3) / 4, 256, 0, stream>>>(att, deg, o_idx, B);
    k_conv1d<<<B / 4, 256, 0, stream>>>(x, (const bf16x8*)d_ws, b1d, o_site, o_asite, B);
    k_conv2d<<<B, 256, 0, stream>>>(x, w2d, b2d, o_idx, o_bag, B);
}